// Round 15
// baseline (603.723 us; speedup 1.0000x reference)
//
#include <hip/hip_runtime.h>
#include <hip/hip_fp16.h>

#define NG 64              // graphs (= Y feature width)
#define NGRAPH_C 64
#define KPAD 10240         // word vocab padded to 32*320

// ---- bit casts ----
__device__ __forceinline__ unsigned f_as_u(float f) { union { float f; unsigned u; } c; c.f = f; return c.u; }
__device__ __forceinline__ float u_as_f(unsigned u) { union { unsigned u; float f; } c; c.u = u; return c.f; }

union H4 { uint2 u2; __half h[4]; };

// ---------------- count: histograms + within-row rank (atomic return) ----------------
__global__ __launch_bounds__(256) void k_count(const int* __restrict__ src, const int* __restrict__ dst,
                                               unsigned* __restrict__ cin, unsigned* __restrict__ csrc,
                                               unsigned* __restrict__ rank, int e) {
    int i = blockIdx.x * 256 + threadIdx.x;
    if (i >= e) return;
    atomicAdd(&cin[dst[i]], 1u);
    rank[i] = atomicAdd(&csrc[src[i]], 1u);
}

// ---------------- blocksum over csrc + dinv from cin (fused) ----------------
__global__ __launch_bounds__(256) void k_blocksum(const unsigned* __restrict__ counts,
                                                  const unsigned* __restrict__ cin,
                                                  float* __restrict__ dinv,
                                                  unsigned* __restrict__ partials, int n) {
    __shared__ unsigned s[256];
    int base = blockIdx.x * 1024;
    unsigned sum = 0;
    for (int j = threadIdx.x; j < 1024; j += 256) {
        int i = base + j;
        if (i < n) {
            sum += counts[i];
            dinv[i] = rsqrtf((float)(cin[i] + 1u));
        }
    }
    s[threadIdx.x] = sum;
    __syncthreads();
    for (int off = 128; off > 0; off >>= 1) {
        if (threadIdx.x < (unsigned)off) s[threadIdx.x] += s[threadIdx.x + off];
        __syncthreads();
    }
    if (threadIdx.x == 0) partials[blockIdx.x] = s[0];
}

__global__ __launch_bounds__(128) void k_scanpartials(unsigned* __restrict__ partials, int nb) {
    __shared__ unsigned s[128];
    int t = threadIdx.x;
    s[t] = (t < nb) ? partials[t] : 0u;
    __syncthreads();
    if (t == 0) {
        unsigned run = 0;
        for (int i = 0; i < nb; ++i) { unsigned v = s[i]; s[i] = run; run += v; }
    }
    __syncthreads();
    if (t < nb) partials[t] = s[t];
}

__global__ __launch_bounds__(256) void k_scanblock(const unsigned* __restrict__ counts,
                                                   const unsigned* __restrict__ partials,
                                                   unsigned* __restrict__ row_start, int n) {
    __shared__ unsigned s[256];
    int base = blockIdx.x * 1024;
    int t = threadIdx.x;
    unsigned v[4];
    unsigned tsum = 0;
#pragma unroll
    for (int j = 0; j < 4; ++j) {
        int i = base + t * 4 + j;
        v[j] = (i < n) ? counts[i] : 0u;
        tsum += v[j];
    }
    s[t] = tsum;
    __syncthreads();
    for (int off = 1; off < 256; off <<= 1) {
        unsigned x = (t >= off) ? s[t - off] : 0u;
        __syncthreads();
        s[t] += x;
        __syncthreads();
    }
    unsigned excl = (t > 0 ? s[t - 1] : 0u) + partials[blockIdx.x];
#pragma unroll
    for (int j = 0; j < 4; ++j) {
        int i = base + t * 4 + j;
        if (i < n) {
            row_start[i] = excl;
            excl += v[j];
            if (i == n - 1) row_start[n] = excl;
        }
    }
}

// ---------------- atomic-free CSR fill: pos = row_start[src] + rank ----------------
// edge record: x = dst | (batch[dst]<<17), y = norm fp32.
__global__ __launch_bounds__(256) void k_fill(const int* __restrict__ src, const int* __restrict__ dst,
                                              const int* __restrict__ batch,
                                              const unsigned* __restrict__ row_start,
                                              const unsigned* __restrict__ rank,
                                              uint2* __restrict__ euv,
                                              const float* __restrict__ dinv, int e) {
    int i = blockIdx.x * 256 + threadIdx.x;
    if (i >= e) return;
    int s0 = src[i], d = dst[i];
    unsigned pos = row_start[s0] + rank[i];
    uint2 p;
    p.x = (unsigned)d | ((unsigned)batch[d] << 17);
    p.y = f_as_u(dinv[s0] * dinv[d]);
    euv[pos] = p;
}

// ---------------- gstart (batch sorted) ----------------
__global__ __launch_bounds__(128) void k_gstart(const int* __restrict__ batch,
                                                int* __restrict__ gstart, int n) {
    int g = threadIdx.x;
    if (g > NGRAPH_C) return;
    if (g == NGRAPH_C) { gstart[g] = n; return; }
    int lo = 0, hi = n;
    while (lo < hi) {
        int mid = (lo + hi) >> 1;
        if (batch[mid] < g) lo = mid + 1; else hi = mid;
    }
    gstart[g] = lo;
}

// ---------------- standalone tiled 300x300 GEMM: C = A*B, 64x64 tiles, 25 blocks ----------------
// As stride 68: 68%4==0 -> float4-aligned; staging write stride 68 banks -> mild 4-way, ok.
__global__ __launch_bounds__(256) void k_mm300(const float* __restrict__ A,
                                               const float* __restrict__ B,
                                               float* __restrict__ C) {
    __shared__ float As[32 * 68];
    __shared__ float Bs[32 * 64];
    int bb = blockIdx.x;
    int t = threadIdx.x;
    int by = bb / 5, bx = bb - by * 5;
    int r0 = by * 64, c0 = bx * 64;
    int tg = t >> 4, tc = t & 15;
    float acc[4][4] = {};
    for (int k0 = 0; k0 < 300; k0 += 32) {
#pragma unroll
        for (int r2 = 0; r2 < 8; ++r2) {
            int u = r2 * 256 + t;          // 0..2047
            int m = u >> 5, k = u & 31;    // k fast -> coalesced global read
            int gm = r0 + m, gk = k0 + k;
            As[k * 68 + m] = (gm < 300 && gk < 300) ? A[gm * 300 + gk] : 0.f;
        }
#pragma unroll
        for (int r2 = 0; r2 < 8; ++r2) {
            int u = r2 * 256 + t;
            int k = u >> 6, nn = u & 63;   // nn fast -> coalesced
            int gk = k0 + k, gn = c0 + nn;
            Bs[k * 64 + nn] = (gk < 300 && gn < 300) ? B[gk * 300 + gn] : 0.f;
        }
        __syncthreads();
#pragma unroll 8
        for (int k = 0; k < 32; ++k) {
            float4 a4 = *(const float4*)&As[k * 68 + tg * 4];
            float4 b4 = *(const float4*)&Bs[k * 64 + tc * 4];
            float a[4] = {a4.x, a4.y, a4.z, a4.w};
            float b[4] = {b4.x, b4.y, b4.z, b4.w};
#pragma unroll
            for (int i = 0; i < 4; ++i)
#pragma unroll
                for (int j = 0; j < 4; ++j) acc[i][j] += a[i] * b[j];
        }
        __syncthreads();
    }
#pragma unroll
    for (int i = 0; i < 4; ++i) {
        int gm = r0 + tg * 4 + i;
        if (gm >= 300) continue;
#pragma unroll
        for (int j = 0; j < 4; ++j) {
            int gn = c0 + tc * 4 + j;
            if (gn < 300) C[gm * 300 + gn] = acc[i][j];
        }
    }
}

// ---------------- r_out = vin^T * W (300x300), thin ----------------
__global__ __launch_bounds__(256) void k_rvec(const float* __restrict__ vin,
                                              const float* __restrict__ W,
                                              float* __restrict__ r_out) {
    int c = blockIdx.x * 256 + threadIdx.x;
    if (c >= 300) return;
    float acc = 0.f;
#pragma unroll 1
    for (int k = 0; k < 300; k += 12) {
        float acc2 = 0.f;
#pragma unroll
        for (int q = 0; q < 12; ++q) acc2 += vin[k + q] * W[(k + q) * 300 + c];
        acc += acc2;
    }
    r_out[c] = acc;
}

// ---------------- hop 1 (fp16 out) ----------------
__global__ __launch_bounds__(256) void k_y1(const int* __restrict__ batch,
                                            const float* __restrict__ dinv,
                                            const unsigned* __restrict__ row_start,
                                            const uint2* __restrict__ euv,
                                            __half* __restrict__ Y1, int n) {
    int idx = blockIdx.x * 256 + threadIdx.x;
    if (idx >= n * 16) return;
    int j = idx >> 4;
    int c4 = idx & 15;
    int cb = c4 * 4;
    float a0 = 0.f, a1 = 0.f, a2 = 0.f, a3 = 0.f;
    {
        int bj = batch[j];
        float dj = dinv[j];
        float sn = dj * dj;
        a0 += (bj == cb + 0) ? sn : 0.f;
        a1 += (bj == cb + 1) ? sn : 0.f;
        a2 += (bj == cb + 2) ? sn : 0.f;
        a3 += (bj == cb + 3) ? sn : 0.f;
    }
    unsigned e0 = row_start[j], e1 = row_start[j + 1];
    for (unsigned e = e0; e < e1; ++e) {
        uint2 p = euv[e];
        int bd = (int)(p.x >> 17);
        float v = u_as_f(p.y);
        a0 += (bd == cb + 0) ? v : 0.f;
        a1 += (bd == cb + 1) ? v : 0.f;
        a2 += (bd == cb + 2) ? v : 0.f;
        a3 += (bd == cb + 3) ? v : 0.f;
    }
    H4 o;
    o.h[0] = __float2half(a0); o.h[1] = __float2half(a1);
    o.h[2] = __float2half(a2); o.h[3] = __float2half(a3);
    *(uint2*)&Y1[(size_t)j * NG + cb] = o.u2;
}

// ---------------- Y-hop fp16 -> fp16 ----------------
__global__ __launch_bounds__(256) void k_yprop(const __half* __restrict__ Yin,
                                               const float* __restrict__ dinv,
                                               const unsigned* __restrict__ row_start,
                                               const uint2* __restrict__ euv,
                                               __half* __restrict__ Yout, int n) {
    int idx = blockIdx.x * 256 + threadIdx.x;
    if (idx >= n * 16) return;
    int j = idx >> 4;
    int c4 = idx & 15;
    int cb = c4 * 4;
    float dj = dinv[j];
    float sn = dj * dj;
    H4 s; s.u2 = *(const uint2*)&Yin[(size_t)j * NG + cb];
    float a0 = sn * __half2float(s.h[0]);
    float a1 = sn * __half2float(s.h[1]);
    float a2 = sn * __half2float(s.h[2]);
    float a3 = sn * __half2float(s.h[3]);
    unsigned e0 = row_start[j], e1 = row_start[j + 1];
    unsigned e = e0;
    for (; e + 2 <= e1; e += 2) {
        uint2 p0 = euv[e], p1 = euv[e + 1];
        float v0 = u_as_f(p0.y), v1 = u_as_f(p1.y);
        H4 m0; m0.u2 = *(const uint2*)&Yin[(size_t)(p0.x & 0x1FFFFu) * NG + cb];
        H4 m1; m1.u2 = *(const uint2*)&Yin[(size_t)(p1.x & 0x1FFFFu) * NG + cb];
        a0 += v0 * __half2float(m0.h[0]) + v1 * __half2float(m1.h[0]);
        a1 += v0 * __half2float(m0.h[1]) + v1 * __half2float(m1.h[1]);
        a2 += v0 * __half2float(m0.h[2]) + v1 * __half2float(m1.h[2]);
        a3 += v0 * __half2float(m0.h[3]) + v1 * __half2float(m1.h[3]);
    }
    if (e < e1) {
        uint2 p0 = euv[e];
        float v0 = u_as_f(p0.y);
        H4 m0; m0.u2 = *(const uint2*)&Yin[(size_t)(p0.x & 0x1FFFFu) * NG + cb];
        a0 += v0 * __half2float(m0.h[0]);
        a1 += v0 * __half2float(m0.h[1]);
        a2 += v0 * __half2float(m0.h[2]);
        a3 += v0 * __half2float(m0.h[3]);
    }
    H4 o;
    o.h[0] = __float2half(a0); o.h[1] = __float2half(a1);
    o.h[2] = __float2half(a2); o.h[3] = __float2half(a3);
    *(uint2*)&Yout[(size_t)j * NG + cb] = o.u2;
}

// ---------------- Y-hop fp16 -> fp32 (final hop) ----------------
__global__ __launch_bounds__(256) void k_yprop3(const __half* __restrict__ Yin,
                                                const float* __restrict__ dinv,
                                                const unsigned* __restrict__ row_start,
                                                const uint2* __restrict__ euv,
                                                float* __restrict__ Yout, int n) {
    int idx = blockIdx.x * 256 + threadIdx.x;
    if (idx >= n * 16) return;
    int j = idx >> 4;
    int c4 = idx & 15;
    int cb = c4 * 4;
    float dj = dinv[j];
    float sn = dj * dj;
    H4 s; s.u2 = *(const uint2*)&Yin[(size_t)j * NG + cb];
    float a0 = sn * __half2float(s.h[0]);
    float a1 = sn * __half2float(s.h[1]);
    float a2 = sn * __half2float(s.h[2]);
    float a3 = sn * __half2float(s.h[3]);
    unsigned e0 = row_start[j], e1 = row_start[j + 1];
    unsigned e = e0;
    for (; e + 2 <= e1; e += 2) {
        uint2 p0 = euv[e], p1 = euv[e + 1];
        float v0 = u_as_f(p0.y), v1 = u_as_f(p1.y);
        H4 m0; m0.u2 = *(const uint2*)&Yin[(size_t)(p0.x & 0x1FFFFu) * NG + cb];
        H4 m1; m1.u2 = *(const uint2*)&Yin[(size_t)(p1.x & 0x1FFFFu) * NG + cb];
        a0 += v0 * __half2float(m0.h[0]) + v1 * __half2float(m1.h[0]);
        a1 += v0 * __half2float(m0.h[1]) + v1 * __half2float(m1.h[1]);
        a2 += v0 * __half2float(m0.h[2]) + v1 * __half2float(m1.h[2]);
        a3 += v0 * __half2float(m0.h[3]) + v1 * __half2float(m1.h[3]);
    }
    if (e < e1) {
        uint2 p0 = euv[e];
        float v0 = u_as_f(p0.y);
        H4 m0; m0.u2 = *(const uint2*)&Yin[(size_t)(p0.x & 0x1FFFFu) * NG + cb];
        a0 += v0 * __half2float(m0.h[0]);
        a1 += v0 * __half2float(m0.h[1]);
        a2 += v0 * __half2float(m0.h[2]);
        a3 += v0 * __half2float(m0.h[3]);
    }
    float4 o; o.x = a0; o.y = a1; o.z = a2; o.w = a3;
    *(float4*)&Yout[(size_t)j * NG + cb] = o;
}

// ---------------- column sums (fp16 input) ----------------
__global__ __launch_bounds__(256) void k_colsumh(const __half* __restrict__ Y,
                                                 float* __restrict__ su, int n) {
    __shared__ float red[4][NG];
    int t = threadIdx.x;
    int g = t & 63;
    int s = t >> 6;
    int per = (n + gridDim.x - 1) / gridDim.x;
    int lo = blockIdx.x * per;
    int hi = min(n, lo + per);
    float acc = 0.f;
    for (int j = lo + s; j < hi; j += 4) acc += __half2float(Y[(size_t)j * NG + g]);
    red[s][g] = acc;
    __syncthreads();
    if (s == 0) atomicAdd(&su[g], red[0][g] + red[1][g] + red[2][g] + red[3][g]);
}

// ---------------- bucket Y3 by vocab ----------------
__global__ __launch_bounds__(256) void k_bucket(const float* __restrict__ Y3,
                                                const int* __restrict__ x,
                                                float* __restrict__ tw,
                                                float* __restrict__ ta, int n) {
    __shared__ float lta[41 * NG];
    int t = threadIdx.x;
    for (int i = t; i < 41 * NG; i += 256) lta[i] = 0.f;
    __syncthreads();
    int g = t & 63;
    int s = t >> 6;
    for (int base = blockIdx.x * 4; base < n; base += gridDim.x * 4) {
        int j = base + s;
        if (j < n) {
            float y = Y3[(size_t)j * NG + g];
            int w = x[2 * j + 1];
            int a = x[2 * j];
            atomicAdd(&tw[(size_t)w * NG + g], y);
            atomicAdd(&lta[a * NG + g], y);
        }
    }
    __syncthreads();
    for (int i = t; i < 41 * NG; i += 256) atomicAdd(&ta[i], lta[i]);
}

// ---------------- tiled word contraction ----------------
__global__ __launch_bounds__(256) void k_wgemm2(const float* __restrict__ T,    // [KPAD][64]
                                                const float* __restrict__ Tab,  // [10000][300]
                                                float* __restrict__ G0) {
    __shared__ float Asm[32 * 64];
    __shared__ float Bsm[32 * 64];
    const int t = threadIdx.x;
    const int tg = t >> 4;
    const int tc = t & 15;
    const int c0 = blockIdx.x * 64;
    const int kb = blockIdx.y * 256;

    float acc[4][4] = {};

    for (int sub = 0; sub < 8; ++sub) {
        int kbase = kb + sub * 32;
#pragma unroll
        for (int r2 = 0; r2 < 2; ++r2) {
            int idx4 = r2 * 256 + t;
            int k = idx4 >> 4, g4 = idx4 & 15;
            float4 v = *(const float4*)&T[(size_t)(kbase + k) * 64 + g4 * 4];
            *(float4*)&Asm[k * 64 + g4 * 4] = v;
        }
#pragma unroll
        for (int r2 = 0; r2 < 2; ++r2) {
            int idx4 = r2 * 256 + t;
            int k = idx4 >> 4, c4i = idx4 & 15;
            int gk = kbase + k;
            int cb2 = c0 + c4i * 4;
            float4 v;
            if (gk < 10000 && cb2 + 3 < 300) {
                v = *(const float4*)&Tab[(size_t)gk * 300 + cb2];
            } else {
                float tmp[4];
#pragma unroll
                for (int q = 0; q < 4; ++q)
                    tmp[q] = (gk < 10000 && cb2 + q < 300) ? Tab[(size_t)gk * 300 + cb2 + q] : 0.f;
                v.x = tmp[0]; v.y = tmp[1]; v.z = tmp[2]; v.w = tmp[3];
            }
            *(float4*)&Bsm[k * 64 + c4i * 4] = v;
        }
        __syncthreads();
#pragma unroll 8
        for (int k = 0; k < 32; ++k) {
            float4 a4 = *(const float4*)&Asm[k * 64 + tg * 4];
            float4 b4 = *(const float4*)&Bsm[k * 64 + tc * 4];
            float a[4] = {a4.x, a4.y, a4.z, a4.w};
            float b[4] = {b4.x, b4.y, b4.z, b4.w};
#pragma unroll
            for (int i = 0; i < 4; ++i)
#pragma unroll
                for (int jj = 0; jj < 4; ++jj) acc[i][jj] += a[i] * b[jj];
        }
        __syncthreads();
    }

#pragma unroll
    for (int i = 0; i < 4; ++i) {
        int g = tg * 4 + i;
#pragma unroll
        for (int jj = 0; jj < 4; ++jj) {
            int c = c0 + tc * 4 + jj;
            if (c < 300) atomicAdd(&G0[g * 300 + c], acc[i][jj]);
        }
    }
}

// ---------------- atom contraction: K=41 ----------------
__global__ __launch_bounds__(256) void k_agemm(const float* __restrict__ T,
                                               const float* __restrict__ Tab,
                                               float* __restrict__ G0) {
    int j = blockIdx.x * 256 + threadIdx.x;
    if (j >= NG * 300) return;
    int g = j / 300, c = j - g * 300;
    float acc = 0.f;
#pragma unroll
    for (int k = 0; k < 41; ++k) acc += T[(size_t)k * NG + g] * Tab[(size_t)k * 300 + c];
    atomicAdd(&G0[j], acc);
}

// ---------------- T3 = G0 * W3 (unroll-12) ----------------
__global__ __launch_bounds__(256) void k_smm(const float* __restrict__ A,
                                             const float* __restrict__ W,
                                             float* __restrict__ C) {
    int j = blockIdx.x * 256 + threadIdx.x;
    if (j >= NG * 300) return;
    int g = j / 300, c = j - g * 300;
    float acc = 0.f;
#pragma unroll 1
    for (int k = 0; k < 300; k += 12) {
        float acc2 = 0.f;
#pragma unroll
        for (int q = 0; q < 12; ++q) acc2 += A[g * 300 + k + q] * W[(k + q) * 300 + c];
        acc += acc2;
    }
    C[j] = acc;
}

// ---------------- final assembly ----------------
__global__ __launch_bounds__(256) void k_out(const float* __restrict__ T3,
                                             const float* __restrict__ su1,
                                             const float* __restrict__ su2,
                                             const int* __restrict__ gstart,
                                             const float* __restrict__ r1,
                                             const float* __restrict__ r2,
                                             const float* __restrict__ b,
                                             float* __restrict__ out) {
    int j = blockIdx.x * 256 + threadIdx.x;
    if (j >= NG * 300) return;
    int g = j / 300, c = j - g * 300;
    int cnt = gstart[g + 1] - gstart[g];
    float v = T3[j] + su2[g] * r2[c] + su1[g] * r1[c] + (float)cnt * b[c];
    out[j] = v / (float)(cnt > 0 ? cnt : 1);
}

// ---------------- launch ----------------
extern "C" void kernel_launch(void* const* d_in, const int* in_sizes, int n_in,
                              void* d_out, int out_size, void* d_ws, size_t ws_size,
                              hipStream_t stream) {
    const int*   x     = (const int*)d_in[0];
    const int*   ei    = (const int*)d_in[1];
    const int*   batch = (const int*)d_in[2];
    const float* at    = (const float*)d_in[3];
    const float* wt    = (const float*)d_in[4];
    const float* W     = (const float*)d_in[5];
    const float* b     = (const float*)d_in[6];

    const int n = in_sizes[0] / 2;   // 100000
    const int e = in_sizes[1] / 2;   // 800000

    char* ws = (char*)d_ws;
    size_t off = 0;
    auto carve = [&](size_t bytes) {
        void* p = ws + off;
        off += (bytes + 255) & ~(size_t)255;
        return p;
    };
    __half*   Y1        = (__half*)carve((size_t)n * NG * 2);
    __half*   Y2        = (__half*)carve((size_t)n * NG * 2);
    float*    Y3        = (float*)carve((size_t)n * NG * 4);
    uint2*    euv       = (uint2*)carve((size_t)e * 8);
    unsigned* rankb     = (unsigned*)carve((size_t)e * 4);
    float*    dinv      = (float*)carve((size_t)n * 4);
    unsigned* row_start = (unsigned*)carve((size_t)(n + 1) * 4);
    unsigned* partials  = (unsigned*)carve(1024 * 4);
    int*      gstart    = (int*)carve(65 * 4);
    float*    W2        = (float*)carve((size_t)300 * 300 * 4);
    float*    W3        = (float*)carve((size_t)300 * 300 * 4);
    float*    r1        = (float*)carve(300 * 4);
    float*    r2        = (float*)carve(300 * 4);
    float*    T3f       = (float*)carve((size_t)NG * 300 * 4);
    // ---- zero region A: histograms ----
    char*     zA0       = (char*)carve(0);
    unsigned* cin       = (unsigned*)carve((size_t)n * 4);
    unsigned* csrc      = (unsigned*)carve((size_t)n * 4);
    char*     zA1       = (char*)carve(0);
    // ---- zero region B: su1, su2, ta, tw(padded), G0 ----
    char*     zB0       = (char*)carve(0);
    float*    su1       = (float*)carve(NG * 4);
    float*    su2       = (float*)carve(NG * 4);
    float*    ta        = (float*)carve((size_t)41 * NG * 4);
    float*    tw        = (float*)carve((size_t)KPAD * NG * 4);
    float*    G0        = (float*)carve((size_t)NG * 300 * 4);
    char*     zB1       = (char*)carve(0);

    const int* src = ei;
    const int* dst = ei + e;

    hipMemsetAsync(zA0, 0, (size_t)(zA1 - zA0), stream);
    hipMemsetAsync(zB0, 0, (size_t)(zB1 - zB0), stream);

    int eb = (e + 255) / 256;        // 3125
    int NB = (n + 1023) / 1024;      // 98

    // graph prep
    k_count<<<eb, 256, 0, stream>>>(src, dst, cin, csrc, rankb, e);
    k_blocksum<<<NB, 256, 0, stream>>>(csrc, cin, dinv, partials, n);
    k_scanpartials<<<1, 128, 0, stream>>>(partials, NB);
    k_scanblock<<<NB, 256, 0, stream>>>(csrc, partials, row_start, n);
    k_fill<<<eb, 256, 0, stream>>>(src, dst, batch, row_start, rankb, euv, dinv, e);
    k_gstart<<<1, 128, 0, stream>>>(batch, gstart, n);

    // W chain (standalone tiled)
    k_mm300<<<25, 256, 0, stream>>>(W, W, W2);
    k_mm300<<<25, 256, 0, stream>>>(W2, W, W3);
    k_rvec<<<2, 256, 0, stream>>>(b, W, r1);
    k_rvec<<<2, 256, 0, stream>>>(r1, W, r2);

    // indicator propagation: Y1 (fp16) -> Y2 (fp16) -> Y3 (fp32)
    int yb = (n * 16 + 255) / 256;   // 6250
    k_y1<<<yb, 256, 0, stream>>>(batch, dinv, row_start, euv, Y1, n);
    k_colsumh<<<100, 256, 0, stream>>>(Y1, su1, n);
    k_yprop<<<yb, 256, 0, stream>>>(Y1, dinv, row_start, euv, Y2, n);
    k_colsumh<<<100, 256, 0, stream>>>(Y2, su2, n);
    k_yprop3<<<yb, 256, 0, stream>>>(Y2, dinv, row_start, euv, Y3, n);

    // bucket Y3 by vocab, contract against embedding tables -> G0 = Y3^T H0
    k_bucket<<<256, 256, 0, stream>>>(Y3, x, tw, ta, n);
    {
        dim3 gw(5, 40);
        k_wgemm2<<<gw, 256, 0, stream>>>(tw, wt, G0);
        k_agemm<<<(NG * 300 + 255) / 256, 256, 0, stream>>>(ta, at, G0);
    }

    // T3 = G0 * W3
    k_smm<<<(NG * 300 + 255) / 256, 256, 0, stream>>>(G0, W3, T3f);

    k_out<<<(NG * 300 + 255) / 256, 256, 0, stream>>>(T3f, su1, su2, gstart, r1, r2, b, (float*)d_out);
}

// Round 16
// 501.967 us; speedup vs baseline: 1.2027x; 1.2027x over previous
//
#include <hip/hip_runtime.h>
#include <hip/hip_fp16.h>

#define NG 64              // graphs (= Y feature width)
#define NGRAPH_C 64
#define KPAD 10240         // word vocab padded to 32*320

// ---- bit casts ----
__device__ __forceinline__ unsigned f_as_u(float f) { union { float f; unsigned u; } c; c.f = f; return c.u; }
__device__ __forceinline__ float u_as_f(unsigned u) { union { unsigned u; float f; } c; c.u = u; return c.f; }

union H4 { uint2 u2; __half h[4]; };

// ---------------- counts: 8-way replicated histograms, fire-and-forget ----------------
__global__ __launch_bounds__(256) void k_count2(const int* __restrict__ src, const int* __restrict__ dst,
                                                unsigned* __restrict__ c8in,
                                                unsigned* __restrict__ c8src, int e, int n) {
    int i = blockIdx.x * 256 + threadIdx.x;
    if (i >= e) return;
    int r = blockIdx.x & 7;
    atomicAdd(&c8in[(size_t)r * n + dst[i]], 1u);
    atomicAdd(&c8src[(size_t)r * n + src[i]], 1u);
}

// reduce replicas: dinv, total out-counts, per-replica exclusive prefixes
__global__ __launch_bounds__(256) void k_reduce8(const unsigned* __restrict__ c8in,
                                                 const unsigned* __restrict__ c8src,
                                                 float* __restrict__ dinv,
                                                 unsigned* __restrict__ counts_src,
                                                 unsigned* __restrict__ pref8, int n) {
    int i = blockIdx.x * 256 + threadIdx.x;
    if (i >= n) return;
    unsigned sin = 0;
#pragma unroll
    for (int r = 0; r < 8; ++r) sin += c8in[(size_t)r * n + i];
    dinv[i] = rsqrtf((float)(sin + 1u));
    unsigned run = 0;
#pragma unroll
    for (int r = 0; r < 8; ++r) {
        pref8[(size_t)r * n + i] = run;
        run += c8src[(size_t)r * n + i];
    }
    counts_src[i] = run;
}

// ---------------- 2-level exclusive scan ----------------
__global__ __launch_bounds__(256) void k_blocksum(const unsigned* __restrict__ counts,
                                                  unsigned* __restrict__ partials, int n) {
    __shared__ unsigned s[256];
    int base = blockIdx.x * 1024;
    unsigned sum = 0;
    for (int j = threadIdx.x; j < 1024; j += 256) {
        int i = base + j;
        sum += (i < n) ? counts[i] : 0u;
    }
    s[threadIdx.x] = sum;
    __syncthreads();
    for (int off = 128; off > 0; off >>= 1) {
        if (threadIdx.x < (unsigned)off) s[threadIdx.x] += s[threadIdx.x + off];
        __syncthreads();
    }
    if (threadIdx.x == 0) partials[blockIdx.x] = s[0];
}

__global__ __launch_bounds__(128) void k_scanpartials(unsigned* __restrict__ partials, int nb) {
    __shared__ unsigned s[128];
    int t = threadIdx.x;
    s[t] = (t < nb) ? partials[t] : 0u;
    __syncthreads();
    if (t == 0) {
        unsigned run = 0;
        for (int i = 0; i < nb; ++i) { unsigned v = s[i]; s[i] = run; run += v; }
    }
    __syncthreads();
    if (t < nb) partials[t] = s[t];
}

__global__ __launch_bounds__(256) void k_scanblock(const unsigned* __restrict__ counts,
                                                   const unsigned* __restrict__ partials,
                                                   unsigned* __restrict__ row_start, int n) {
    __shared__ unsigned s[256];
    int base = blockIdx.x * 1024;
    int t = threadIdx.x;
    unsigned v[4];
    unsigned tsum = 0;
#pragma unroll
    for (int j = 0; j < 4; ++j) {
        int i = base + t * 4 + j;
        v[j] = (i < n) ? counts[i] : 0u;
        tsum += v[j];
    }
    s[t] = tsum;
    __syncthreads();
    for (int off = 1; off < 256; off <<= 1) {
        unsigned x = (t >= off) ? s[t - off] : 0u;
        __syncthreads();
        s[t] += x;
        __syncthreads();
    }
    unsigned excl = (t > 0 ? s[t - 1] : 0u) + partials[blockIdx.x];
#pragma unroll
    for (int j = 0; j < 4; ++j) {
        int i = base + t * 4 + j;
        if (i < n) {
            row_start[i] = excl;
            excl += v[j];
            if (i == n - 1) row_start[n] = excl;
        }
    }
}

// ---------------- reverse-CSR fill (8-way cursors): uint2 edge = (dst|batch<<17, norm) ----------------
__global__ __launch_bounds__(256) void k_fill(const int* __restrict__ src, const int* __restrict__ dst,
                                              const int* __restrict__ batch,
                                              const unsigned* __restrict__ row_start,
                                              const unsigned* __restrict__ pref8,
                                              unsigned* __restrict__ fillc8,
                                              uint2* __restrict__ euv,
                                              const float* __restrict__ dinv, int e, int n) {
    int i = blockIdx.x * 256 + threadIdx.x;
    if (i >= e) return;
    int r = blockIdx.x & 7;     // must match k_count2's mapping (same grid)
    int s0 = src[i], d = dst[i];
    unsigned pos = row_start[s0] + pref8[(size_t)r * n + s0]
                 + atomicAdd(&fillc8[(size_t)r * n + s0], 1u);
    uint2 p;
    p.x = (unsigned)d | ((unsigned)batch[d] << 17);
    p.y = f_as_u(dinv[s0] * dinv[d]);
    euv[pos] = p;
}

// ---------------- graph boundaries (batch sorted) ----------------
__global__ __launch_bounds__(128) void k_gstart(const int* __restrict__ batch,
                                                int* __restrict__ gstart, int n, int ngraph) {
    int g = threadIdx.x;
    if (g > ngraph) return;
    if (g == ngraph) { gstart[g] = n; return; }
    int lo = 0, hi = n;
    while (lo < hi) {
        int mid = (lo + hi) >> 1;
        if (batch[mid] < g) lo = mid + 1; else hi = mid;
    }
    gstart[g] = lo;
}

// ---------------- hop 1 (fp16 out) ----------------
__global__ __launch_bounds__(256) void k_y1(const int* __restrict__ batch,
                                            const float* __restrict__ dinv,
                                            const unsigned* __restrict__ row_start,
                                            const uint2* __restrict__ euv,
                                            __half* __restrict__ Y1, int n) {
    int idx = blockIdx.x * 256 + threadIdx.x;
    if (idx >= n * 16) return;
    int j = idx >> 4;
    int c4 = idx & 15;
    int cb = c4 * 4;
    float a0 = 0.f, a1 = 0.f, a2 = 0.f, a3 = 0.f;
    {
        int bj = batch[j];
        float dj = dinv[j];
        float sn = dj * dj;
        a0 += (bj == cb + 0) ? sn : 0.f;
        a1 += (bj == cb + 1) ? sn : 0.f;
        a2 += (bj == cb + 2) ? sn : 0.f;
        a3 += (bj == cb + 3) ? sn : 0.f;
    }
    unsigned e0 = row_start[j], e1 = row_start[j + 1];
    for (unsigned e = e0; e < e1; ++e) {
        uint2 p = euv[e];
        int bd = (int)(p.x >> 17);
        float v = u_as_f(p.y);
        a0 += (bd == cb + 0) ? v : 0.f;
        a1 += (bd == cb + 1) ? v : 0.f;
        a2 += (bd == cb + 2) ? v : 0.f;
        a3 += (bd == cb + 3) ? v : 0.f;
    }
    H4 o;
    o.h[0] = __float2half(a0); o.h[1] = __float2half(a1);
    o.h[2] = __float2half(a2); o.h[3] = __float2half(a3);
    *(uint2*)&Y1[(size_t)j * NG + cb] = o.u2;
}

// ---------------- Y-hop fp16 -> fp16 ----------------
__global__ __launch_bounds__(256) void k_yprop(const __half* __restrict__ Yin,
                                               const float* __restrict__ dinv,
                                               const unsigned* __restrict__ row_start,
                                               const uint2* __restrict__ euv,
                                               __half* __restrict__ Yout, int n) {
    int idx = blockIdx.x * 256 + threadIdx.x;
    if (idx >= n * 16) return;
    int j = idx >> 4;
    int c4 = idx & 15;
    int cb = c4 * 4;
    float dj = dinv[j];
    float sn = dj * dj;
    H4 s; s.u2 = *(const uint2*)&Yin[(size_t)j * NG + cb];
    float a0 = sn * __half2float(s.h[0]);
    float a1 = sn * __half2float(s.h[1]);
    float a2 = sn * __half2float(s.h[2]);
    float a3 = sn * __half2float(s.h[3]);
    unsigned e0 = row_start[j], e1 = row_start[j + 1];
    unsigned e = e0;
    for (; e + 2 <= e1; e += 2) {
        uint2 p0 = euv[e], p1 = euv[e + 1];
        float v0 = u_as_f(p0.y), v1 = u_as_f(p1.y);
        H4 m0; m0.u2 = *(const uint2*)&Yin[(size_t)(p0.x & 0x1FFFFu) * NG + cb];
        H4 m1; m1.u2 = *(const uint2*)&Yin[(size_t)(p1.x & 0x1FFFFu) * NG + cb];
        a0 += v0 * __half2float(m0.h[0]) + v1 * __half2float(m1.h[0]);
        a1 += v0 * __half2float(m0.h[1]) + v1 * __half2float(m1.h[1]);
        a2 += v0 * __half2float(m0.h[2]) + v1 * __half2float(m1.h[2]);
        a3 += v0 * __half2float(m0.h[3]) + v1 * __half2float(m1.h[3]);
    }
    if (e < e1) {
        uint2 p0 = euv[e];
        float v0 = u_as_f(p0.y);
        H4 m0; m0.u2 = *(const uint2*)&Yin[(size_t)(p0.x & 0x1FFFFu) * NG + cb];
        a0 += v0 * __half2float(m0.h[0]);
        a1 += v0 * __half2float(m0.h[1]);
        a2 += v0 * __half2float(m0.h[2]);
        a3 += v0 * __half2float(m0.h[3]);
    }
    H4 o;
    o.h[0] = __float2half(a0); o.h[1] = __float2half(a1);
    o.h[2] = __float2half(a2); o.h[3] = __float2half(a3);
    *(uint2*)&Yout[(size_t)j * NG + cb] = o.u2;
}

// ---------------- column sums (fp16 input) ----------------
__global__ __launch_bounds__(256) void k_colsumh(const __half* __restrict__ Y,
                                                 float* __restrict__ su, int n) {
    __shared__ float red[4][NG];
    int t = threadIdx.x;
    int g = t & 63;
    int s = t >> 6;
    int per = (n + gridDim.x - 1) / gridDim.x;
    int lo = blockIdx.x * per;
    int hi = min(n, lo + per);
    float acc = 0.f;
    for (int j = lo + s; j < hi; j += 4) acc += __half2float(Y[(size_t)j * NG + g]);
    red[s][g] = acc;
    __syncthreads();
    if (s == 0) atomicAdd(&su[g], red[0][g] + red[1][g] + red[2][g] + red[3][g]);
}

// ---------------- bucket Y3 (fp16) by vocab ----------------
__global__ __launch_bounds__(256) void k_bucket(const __half* __restrict__ Y3,
                                                const int* __restrict__ x,
                                                float* __restrict__ tw,
                                                float* __restrict__ ta, int n) {
    __shared__ float lta[41 * NG];
    int t = threadIdx.x;
    for (int i = t; i < 41 * NG; i += 256) lta[i] = 0.f;
    __syncthreads();
    int g = t & 63;
    int s = t >> 6;
    for (int base = blockIdx.x * 4; base < n; base += gridDim.x * 4) {
        int j = base + s;
        if (j < n) {
            float y = __half2float(Y3[(size_t)j * NG + g]);
            int w = x[2 * j + 1];
            int a = x[2 * j];
            atomicAdd(&tw[(size_t)w * NG + g], y);
            atomicAdd(&lta[a * NG + g], y);
        }
    }
    __syncthreads();
    for (int i = t; i < 41 * NG; i += 256) atomicAdd(&ta[i], lta[i]);
}

// ---------------- tiled word contraction ----------------
__global__ __launch_bounds__(256) void k_wgemm2(const float* __restrict__ T,    // [KPAD][64]
                                                const float* __restrict__ Tab,  // [10000][300]
                                                float* __restrict__ G0) {
    __shared__ float Asm[32 * 64];
    __shared__ float Bsm[32 * 64];
    const int t = threadIdx.x;
    const int tg = t >> 4;
    const int tc = t & 15;
    const int c0 = blockIdx.x * 64;
    const int kb = blockIdx.y * 256;

    float acc[4][4] = {};

    for (int sub = 0; sub < 8; ++sub) {
        int kbase = kb + sub * 32;
#pragma unroll
        for (int r2 = 0; r2 < 2; ++r2) {
            int idx4 = r2 * 256 + t;
            int k = idx4 >> 4, g4 = idx4 & 15;
            float4 v = *(const float4*)&T[(size_t)(kbase + k) * 64 + g4 * 4];
            *(float4*)&Asm[k * 64 + g4 * 4] = v;
        }
#pragma unroll
        for (int r2 = 0; r2 < 2; ++r2) {
            int idx4 = r2 * 256 + t;
            int k = idx4 >> 4, c4i = idx4 & 15;
            int gk = kbase + k;
            int cb2 = c0 + c4i * 4;
            float4 v;
            if (gk < 10000 && cb2 + 3 < 300) {
                v = *(const float4*)&Tab[(size_t)gk * 300 + cb2];
            } else {
                float tmp[4];
#pragma unroll
                for (int q = 0; q < 4; ++q)
                    tmp[q] = (gk < 10000 && cb2 + q < 300) ? Tab[(size_t)gk * 300 + cb2 + q] : 0.f;
                v.x = tmp[0]; v.y = tmp[1]; v.z = tmp[2]; v.w = tmp[3];
            }
            *(float4*)&Bsm[k * 64 + c4i * 4] = v;
        }
        __syncthreads();
#pragma unroll 8
        for (int k = 0; k < 32; ++k) {
            float4 a4 = *(const float4*)&Asm[k * 64 + tg * 4];
            float4 b4 = *(const float4*)&Bsm[k * 64 + tc * 4];
            float a[4] = {a4.x, a4.y, a4.z, a4.w};
            float b[4] = {b4.x, b4.y, b4.z, b4.w};
#pragma unroll
            for (int i = 0; i < 4; ++i)
#pragma unroll
                for (int jj = 0; jj < 4; ++jj) acc[i][jj] += a[i] * b[jj];
        }
        __syncthreads();
    }

#pragma unroll
    for (int i = 0; i < 4; ++i) {
        int g = tg * 4 + i;
#pragma unroll
        for (int jj = 0; jj < 4; ++jj) {
            int c = c0 + tc * 4 + jj;
            if (c < 300) atomicAdd(&G0[g * 300 + c], acc[i][jj]);
        }
    }
}

// ---------------- atom contraction: K=41 ----------------
__global__ __launch_bounds__(256) void k_agemm(const float* __restrict__ T,
                                               const float* __restrict__ Tab,
                                               float* __restrict__ G0) {
    int j = blockIdx.x * 256 + threadIdx.x;
    if (j >= NG * 300) return;
    int g = j / 300, c = j - g * 300;
    float acc = 0.f;
#pragma unroll
    for (int k = 0; k < 41; ++k) acc += T[(size_t)k * NG + g] * Tab[(size_t)k * 300 + c];
    atomicAdd(&G0[j], acc);
}

// ---------------- small GEMM split-k: C[64x300] += A[64x300] * W[300x300], 5 chunks of 60 ----------------
__global__ __launch_bounds__(256) void k_smm(const float* __restrict__ A,
                                             const float* __restrict__ W,
                                             float* __restrict__ C) {
    int j = blockIdx.x * 256 + threadIdx.x;
    if (j >= NG * 300) return;
    int g = j / 300, c = j - g * 300;
    int k0 = blockIdx.y * 60;
    float acc = 0.f;
#pragma unroll 1
    for (int k = k0; k < k0 + 60; k += 4) {
        float a0 = A[g * 300 + k + 0], a1 = A[g * 300 + k + 1];
        float a2 = A[g * 300 + k + 2], a3 = A[g * 300 + k + 3];
        float w0 = W[(k + 0) * 300 + c], w1 = W[(k + 1) * 300 + c];
        float w2 = W[(k + 2) * 300 + c], w3 = W[(k + 3) * 300 + c];
        acc += a0 * w0 + a1 * w1 + a2 * w2 + a3 * w3;
    }
    atomicAdd(&C[j], acc);
}

// ---------------- vector-matrix: r_out[c] += sum_k vin[k] * W[k][c] (split-k) ----------------
__global__ __launch_bounds__(256) void k_vec(const float* __restrict__ vin,
                                             const float* __restrict__ W,
                                             float* __restrict__ r_out) {
    int c = blockIdx.x * 256 + threadIdx.x;
    if (c >= 300) return;
    int k0 = blockIdx.y * 75;
    float acc = 0.f;
    for (int k = k0; k < k0 + 75; ++k) acc += vin[k] * W[k * 300 + c];
    atomicAdd(&r_out[c], acc);
}

// ---------------- final assembly ----------------
__global__ __launch_bounds__(256) void k_out(const float* __restrict__ T3,
                                             const float* __restrict__ su1,
                                             const float* __restrict__ su2,
                                             const int* __restrict__ gstart,
                                             const float* __restrict__ r1,
                                             const float* __restrict__ r2,
                                             const float* __restrict__ b,
                                             float* __restrict__ out) {
    int j = blockIdx.x * 256 + threadIdx.x;
    if (j >= NG * 300) return;
    int g = j / 300, c = j - g * 300;
    int cnt = gstart[g + 1] - gstart[g];
    float v = T3[j] + su2[g] * r2[c] + su1[g] * r1[c] + (float)cnt * b[c];
    out[j] = v / (float)(cnt > 0 ? cnt : 1);
}

// ---------------- launch ----------------
extern "C" void kernel_launch(void* const* d_in, const int* in_sizes, int n_in,
                              void* d_out, int out_size, void* d_ws, size_t ws_size,
                              hipStream_t stream) {
    const int*   x     = (const int*)d_in[0];
    const int*   ei    = (const int*)d_in[1];
    const int*   batch = (const int*)d_in[2];
    const float* at    = (const float*)d_in[3];
    const float* wt    = (const float*)d_in[4];
    const float* W     = (const float*)d_in[5];
    const float* b     = (const float*)d_in[6];

    const int n = in_sizes[0] / 2;   // 100000
    const int e = in_sizes[1] / 2;   // 800000

    char* ws = (char*)d_ws;
    size_t off = 0;
    auto carve = [&](size_t bytes) {
        void* p = ws + off;
        off += (bytes + 255) & ~(size_t)255;
        return p;
    };
    __half*   Y1        = (__half*)carve((size_t)n * NG * 2);
    __half*   Y2        = (__half*)carve((size_t)n * NG * 2);
    __half*   Y3        = (__half*)carve((size_t)n * NG * 2);
    uint2*    euv       = (uint2*)carve((size_t)e * 8);
    float*    dinv      = (float*)carve((size_t)n * 4);
    unsigned* counts_src= (unsigned*)carve((size_t)n * 4);
    unsigned* pref8     = (unsigned*)carve((size_t)8 * n * 4);
    unsigned* row_start = (unsigned*)carve((size_t)(n + 1) * 4);
    unsigned* partials  = (unsigned*)carve(1024 * 4);
    int*      gstart    = (int*)carve(65 * 4);
    // ---- zero region A: replicated counters + fill cursors ----
    char*     zA0       = (char*)carve(0);
    unsigned* c8in      = (unsigned*)carve((size_t)8 * n * 4);
    unsigned* c8src     = (unsigned*)carve((size_t)8 * n * 4);
    unsigned* fillc8    = (unsigned*)carve((size_t)8 * n * 4);
    char*     zA1       = (char*)carve(0);
    // ---- zero region B: su1, su2, ta, tw(padded), G0, r1, r2, T1..T3 ----
    char*     zB0       = (char*)carve(0);
    float*    su1       = (float*)carve(NG * 4);
    float*    su2       = (float*)carve(NG * 4);
    float*    ta        = (float*)carve((size_t)41 * NG * 4);
    float*    tw        = (float*)carve((size_t)KPAD * NG * 4);
    float*    G0        = (float*)carve((size_t)NG * 300 * 4);
    float*    r1        = (float*)carve(300 * 4);
    float*    r2        = (float*)carve(300 * 4);
    float*    T1        = (float*)carve((size_t)NG * 300 * 4);
    float*    T2        = (float*)carve((size_t)NG * 300 * 4);
    float*    T3        = (float*)carve((size_t)NG * 300 * 4);
    char*     zB1       = (char*)carve(0);

    const int* src = ei;
    const int* dst = ei + e;

    hipMemsetAsync(zA0, 0, (size_t)(zA1 - zA0), stream);
    hipMemsetAsync(zB0, 0, (size_t)(zB1 - zB0), stream);

    int eb = (e + 255) / 256;        // 3125
    int nb256 = (n + 255) / 256;
    int NB = (n + 1023) / 1024;      // 98

    // graph prep (reverse CSR via 8-way replicated histograms, fire-and-forget)
    k_count2<<<eb, 256, 0, stream>>>(src, dst, c8in, c8src, e, n);
    k_reduce8<<<nb256, 256, 0, stream>>>(c8in, c8src, dinv, counts_src, pref8, n);
    k_blocksum<<<NB, 256, 0, stream>>>(counts_src, partials, n);
    k_scanpartials<<<1, 128, 0, stream>>>(partials, NB);
    k_scanblock<<<NB, 256, 0, stream>>>(counts_src, partials, row_start, n);
    k_fill<<<eb, 256, 0, stream>>>(src, dst, batch, row_start, pref8, fillc8, euv, dinv, e, n);
    k_gstart<<<1, 128, 0, stream>>>(batch, gstart, n, NGRAPH_C);

    // indicator propagation: Y1 (fp16) -> Y2 (fp16) -> Y3 (fp16)
    int yb = (n * 16 + 255) / 256;   // 6250
    k_y1<<<yb, 256, 0, stream>>>(batch, dinv, row_start, euv, Y1, n);
    k_colsumh<<<100, 256, 0, stream>>>(Y1, su1, n);
    k_yprop<<<yb, 256, 0, stream>>>(Y1, dinv, row_start, euv, Y2, n);
    k_colsumh<<<100, 256, 0, stream>>>(Y2, su2, n);
    k_yprop<<<yb, 256, 0, stream>>>(Y2, dinv, row_start, euv, Y3, n);

    // bucket Y3 by vocab, contract against embedding tables -> G0 = Y3^T H0
    k_bucket<<<256, 256, 0, stream>>>(Y3, x, tw, ta, n);
    {
        dim3 gw(5, 40);   // tiled: 5 c-tiles x 40 K-chunks of 256 (KPAD=10240)
        k_wgemm2<<<gw, 256, 0, stream>>>(tw, wt, G0);
        k_agemm<<<(NG * 300 + 255) / 256, 256, 0, stream>>>(ta, at, G0);
    }

    // W chain: T3 = G0 * W^3 (split-k, atomic into zeroed buffers)
    {
        dim3 gs((NG * 300 + 255) / 256, 5);
        k_smm<<<gs, 256, 0, stream>>>(G0, W, T1);
        k_smm<<<gs, 256, 0, stream>>>(T1, W, T2);
        k_smm<<<gs, 256, 0, stream>>>(T2, W, T3);
        dim3 gv(2, 4);
        k_vec<<<gv, 256, 0, stream>>>(b, W, r1);
        k_vec<<<gv, 256, 0, stream>>>(r1, W, r2);
    }

    k_out<<<(NG * 300 + 255) / 256, 256, 0, stream>>>(T3, su1, su2, gstart, r1, r2, b, (float*)d_out);
}